// Round 3
// baseline (1437.360 us; speedup 1.0000x reference)
//
#include <hip/hip_runtime.h>

typedef unsigned short u16;
typedef __bf16 bf16_t;
typedef bf16_t bf16x8 __attribute__((ext_vector_type(8)));
typedef float f32x4 __attribute__((ext_vector_type(4)));

#define D_MODEL 2048
#define SEQ     2048
#define NHEAD   16
#define HDIM    128
#define IDIM    8192

// ---------- helpers ----------
__device__ __forceinline__ u16 f2bf(float f) {
    unsigned u = __float_as_uint(f);
    u += 0x7fffu + ((u >> 16) & 1u);           // RNE
    return (u16)(u >> 16);
}
__device__ __forceinline__ float bf2f(u16 u) {
    return __uint_as_float(((unsigned)u) << 16);
}
__device__ __forceinline__ void gload16(const void* g, void* l) {
    __builtin_amdgcn_global_load_lds(
        (const __attribute__((address_space(1))) unsigned int*)g,
        (__attribute__((address_space(3))) unsigned int*)l, 16, 0, 0);
}
#define MFMA16(a, b, c) __builtin_amdgcn_mfma_f32_16x16x32_bf16((a), (b), (c), 0, 0, 0)

// ---------- RMSNorm: fp32 in -> bf16 out ----------
__global__ __launch_bounds__(256) void rmsnorm_kernel(
    const float* __restrict__ x, const float* __restrict__ w, u16* __restrict__ out)
{
    int row = blockIdx.x, t = threadIdx.x;
    const float4* xr = (const float4*)(x + (size_t)row * D_MODEL);
    float4 a = xr[t * 2], b = xr[t * 2 + 1];
    float ss = a.x*a.x + a.y*a.y + a.z*a.z + a.w*a.w
             + b.x*b.x + b.y*b.y + b.z*b.z + b.w*b.w;
#pragma unroll
    for (int off = 32; off > 0; off >>= 1) ss += __shfl_down(ss, off, 64);
    __shared__ float red[4];
    __shared__ float sinv;
    if ((t & 63) == 0) red[t >> 6] = ss;
    __syncthreads();
    if (t == 0) sinv = rsqrtf((red[0] + red[1] + red[2] + red[3]) * (1.0f / D_MODEL) + 1e-5f);
    __syncthreads();
    float inv = sinv;
    const float4* w4 = (const float4*)w;
    float4 wa = w4[t * 2], wb = w4[t * 2 + 1];
    u16* o = out + (size_t)row * D_MODEL + t * 8;
    o[0] = f2bf(a.x * inv * wa.x); o[1] = f2bf(a.y * inv * wa.y);
    o[2] = f2bf(a.z * inv * wa.z); o[3] = f2bf(a.w * inv * wa.w);
    o[4] = f2bf(b.x * inv * wb.x); o[5] = f2bf(b.y * inv * wb.y);
    o[6] = f2bf(b.z * inv * wb.z); o[7] = f2bf(b.w * inv * wb.w);
}

// ---------- transpose + fp32->bf16 : src[R][C] -> dst[C][R] ----------
__global__ __launch_bounds__(256) void tcvt_kernel(
    const float* __restrict__ src, u16* __restrict__ dst, int R, int C)
{
    __shared__ float tile[32][33];
    int tx = threadIdx.x & 31, ty = threadIdx.x >> 5;
    int c = blockIdx.x * 32 + tx;
    int rb = blockIdx.y * 32;
#pragma unroll
    for (int i = 0; i < 32; i += 8)
        tile[ty + i][tx] = src[(size_t)(rb + ty + i) * C + c];
    __syncthreads();
    int dr = blockIdx.x * 32 + ty;
    int dc = rb + tx;
#pragma unroll
    for (int i = 0; i < 32; i += 8)
        dst[(size_t)(dr + i) * R + dc] = f2bf(tile[tx][ty + i]);
}

// ---------- bf16 transpose : src[R][C] -> dst[C][R] ----------
__global__ __launch_bounds__(256) void tbf16_kernel(
    const u16* __restrict__ src, u16* __restrict__ dst, int R, int C)
{
    __shared__ u16 tile[32][34];
    int tx = threadIdx.x & 31, ty = threadIdx.x >> 5;
    int c = blockIdx.x * 32 + tx;
    int rb = blockIdx.y * 32;
#pragma unroll
    for (int i = 0; i < 32; i += 8)
        tile[ty + i][tx] = src[(size_t)(rb + ty + i) * C + c];
    __syncthreads();
    int dr = blockIdx.x * 32 + ty;
    int dc = rb + tx;
#pragma unroll
    for (int i = 0; i < 32; i += 8)
        dst[(size_t)(dr + i) * R + dc] = tile[tx][ty + i];
}

// ---------- RoPE in-place on q,k (bf16), fp32 tables ----------
__global__ __launch_bounds__(256) void rope_kernel(
    u16* __restrict__ q, u16* __restrict__ k,
    const float* __restrict__ fc, const float* __restrict__ fs)
{
    int s = blockIdx.x, t = threadIdx.x;
    const float* cr = fc + (size_t)s * HDIM;
    const float* sr = fs + (size_t)s * HDIM;
#pragma unroll
    for (int p = 0; p < 4; p++) {
        int pi = p * 256 + t;
        int h = pi >> 6, d = pi & 63;
        size_t base = (size_t)s * D_MODEL + h * HDIM + d;
        float c1 = cr[d], s1 = sr[d], c2 = cr[d + 64], s2 = sr[d + 64];
        float q1 = bf2f(q[base]), q2 = bf2f(q[base + 64]);
        q[base]      = f2bf(q1 * c1 - q2 * s1);
        q[base + 64] = f2bf(q2 * c2 + q1 * s2);
        float k1 = bf2f(k[base]), k2 = bf2f(k[base + 64]);
        k[base]      = f2bf(k1 * c1 - k2 * s1);
        k[base + 64] = f2bf(k2 * c2 + k1 * s2);
    }
}

// ---------- GEMM C = A @ Bt^T  (A:[M][K] bf16, Bt:[N][K] bf16) ----------
// 128x128 tile, 4 waves (2x2), each wave 4x4 16x16x32 MFMAs, BK=32.
// LDS blocked-K layout [kb][128 rows][8 bf16] => fetch order == LDS order.
// EPI 0: bf16 store.  EPI 1: out_f32 = res_f32 + acc.
template <int EPI>
__global__ __launch_bounds__(256) void gemm_bt(
    const u16* __restrict__ A, const u16* __restrict__ Bt,
    const float* __restrict__ res, float* __restrict__ outf, u16* __restrict__ outb,
    int M, int N, int K)
{
    __shared__ __align__(16) u16 lA[128 * 32];
    __shared__ __align__(16) u16 lB[128 * 32];
    int t = threadIdx.x;
    int wave = t >> 6, lane = t & 63, quad = lane >> 4, l16 = lane & 15;
    int wr = wave >> 1, wc = wave & 1;
    int m0 = blockIdx.y * 128, n0 = blockIdx.x * 128;

    const f32x4 fzero = {0.f, 0.f, 0.f, 0.f};
    f32x4 acc[4][4];
#pragma unroll
    for (int i = 0; i < 4; i++)
#pragma unroll
        for (int j = 0; j < 4; j++) acc[i][j] = fzero;

    int c0 = t, c1 = 256 + t;
    int kb0 = c0 >> 7, r0 = c0 & 127;
    int kb1 = c1 >> 7, r1 = c1 & 127;
    const u16* gA0 = A + (size_t)(m0 + r0) * K + kb0 * 8;
    const u16* gA1 = A + (size_t)(m0 + r1) * K + kb1 * 8;
    const u16* gB0 = Bt + (size_t)(n0 + r0) * K + kb0 * 8;
    const u16* gB1 = Bt + (size_t)(n0 + r1) * K + kb1 * 8;
    u16* lA0 = &lA[c0 * 8]; u16* lA1 = &lA[c1 * 8];
    u16* lB0 = &lB[c0 * 8]; u16* lB1 = &lB[c1 * 8];

    for (int k0 = 0; k0 < K; k0 += 32) {
        gload16(gA0 + k0, lA0);
        gload16(gA1 + k0, lA1);
        gload16(gB0 + k0, lB0);
        gload16(gB1 + k0, lB1);
        asm volatile("s_waitcnt vmcnt(0)" ::: "memory");
        __syncthreads();
        bf16x8 af[4], bfv[4];
#pragma unroll
        for (int i = 0; i < 4; i++)
            af[i] = *(const bf16x8*)&lA[quad * 1024 + (wr * 64 + i * 16 + l16) * 8];
#pragma unroll
        for (int j = 0; j < 4; j++)
            bfv[j] = *(const bf16x8*)&lB[quad * 1024 + (wc * 64 + j * 16 + l16) * 8];
#pragma unroll
        for (int i = 0; i < 4; i++)
#pragma unroll
            for (int j = 0; j < 4; j++)
                acc[i][j] = MFMA16(af[i], bfv[j], acc[i][j]);
        __syncthreads();
    }

#pragma unroll
    for (int i = 0; i < 4; i++)
#pragma unroll
        for (int j = 0; j < 4; j++)
#pragma unroll
            for (int r = 0; r < 4; r++) {
                int m = m0 + wr * 64 + i * 16 + quad * 4 + r;
                int n = n0 + wc * 64 + j * 16 + l16;
                size_t idx = (size_t)m * N + n;
                float v = acc[i][j][r];
                if (EPI == 0) outb[idx] = f2bf(v);
                else          outf[idx] = res[idx] + v;
            }
}

// ---------- fused FFN gate GEMM: out = silu(A@B1t^T) * (A@B3t^T), bf16 ----------
__global__ __launch_bounds__(256) void gemm_ffn(
    const u16* __restrict__ A, const u16* __restrict__ B1t, const u16* __restrict__ B3t,
    u16* __restrict__ out, int M, int N, int K)
{
    __shared__ __align__(16) u16 lA[128 * 32];
    __shared__ __align__(16) u16 lB1[128 * 32];
    __shared__ __align__(16) u16 lB3[128 * 32];
    int t = threadIdx.x;
    int wave = t >> 6, lane = t & 63, quad = lane >> 4, l16 = lane & 15;
    int wr = wave >> 1, wc = wave & 1;
    int m0 = blockIdx.y * 128, n0 = blockIdx.x * 128;

    const f32x4 fzero = {0.f, 0.f, 0.f, 0.f};
    f32x4 acc1[4][4], acc3[4][4];
#pragma unroll
    for (int i = 0; i < 4; i++)
#pragma unroll
        for (int j = 0; j < 4; j++) { acc1[i][j] = fzero; acc3[i][j] = fzero; }

    int c0 = t, c1 = 256 + t;
    int kb0 = c0 >> 7, r0 = c0 & 127;
    int kb1 = c1 >> 7, r1 = c1 & 127;
    const u16* gA0 = A + (size_t)(m0 + r0) * K + kb0 * 8;
    const u16* gA1 = A + (size_t)(m0 + r1) * K + kb1 * 8;
    const u16* g10 = B1t + (size_t)(n0 + r0) * K + kb0 * 8;
    const u16* g11 = B1t + (size_t)(n0 + r1) * K + kb1 * 8;
    const u16* g30 = B3t + (size_t)(n0 + r0) * K + kb0 * 8;
    const u16* g31 = B3t + (size_t)(n0 + r1) * K + kb1 * 8;

    for (int k0 = 0; k0 < K; k0 += 32) {
        gload16(gA0 + k0, &lA[c0 * 8]);
        gload16(gA1 + k0, &lA[c1 * 8]);
        gload16(g10 + k0, &lB1[c0 * 8]);
        gload16(g11 + k0, &lB1[c1 * 8]);
        gload16(g30 + k0, &lB3[c0 * 8]);
        gload16(g31 + k0, &lB3[c1 * 8]);
        asm volatile("s_waitcnt vmcnt(0)" ::: "memory");
        __syncthreads();
        bf16x8 af[4], b1[4], b3[4];
#pragma unroll
        for (int i = 0; i < 4; i++)
            af[i] = *(const bf16x8*)&lA[quad * 1024 + (wr * 64 + i * 16 + l16) * 8];
#pragma unroll
        for (int j = 0; j < 4; j++) {
            b1[j] = *(const bf16x8*)&lB1[quad * 1024 + (wc * 64 + j * 16 + l16) * 8];
            b3[j] = *(const bf16x8*)&lB3[quad * 1024 + (wc * 64 + j * 16 + l16) * 8];
        }
#pragma unroll
        for (int i = 0; i < 4; i++)
#pragma unroll
            for (int j = 0; j < 4; j++) {
                acc1[i][j] = MFMA16(af[i], b1[j], acc1[i][j]);
                acc3[i][j] = MFMA16(af[i], b3[j], acc3[i][j]);
            }
        __syncthreads();
    }

#pragma unroll
    for (int i = 0; i < 4; i++)
#pragma unroll
        for (int j = 0; j < 4; j++)
#pragma unroll
            for (int r = 0; r < 4; r++) {
                int m = m0 + wr * 64 + i * 16 + quad * 4 + r;
                int n = n0 + wc * 64 + j * 16 + l16;
                float v1 = acc1[i][j][r], v3 = acc3[i][j][r];
                float hh = v1 / (1.f + __expf(-v1)) * v3;
                out[(size_t)m * N + n] = f2bf(hh);
            }
}

// ---------- flash attention: one block per (q-tile 128, head) ----------
__global__ __launch_bounds__(256, 1) void attn_kernel(
    const u16* __restrict__ q, const u16* __restrict__ k,
    const u16* __restrict__ vt, u16* __restrict__ ctx)
{
    __shared__ __align__(16) u16 sQ[128 * 128];
    __shared__ __align__(16) u16 sK[128 * 128];   // reused as P after QK^T
    __shared__ __align__(16) u16 sV[128 * 128];   // V^T tile [d][s]
    __shared__ float sRed[2][128];
    __shared__ float sM[128];
    __shared__ float sL[128];

    int t = threadIdx.x;
    int wave = t >> 6, lane = t & 63, quad = lane >> 4, l16 = lane & 15;
    int wr = wave >> 1, wc = wave & 1;
    int h = blockIdx.y, qt = blockIdx.x;
    int q0 = qt * 128;

#pragma unroll
    for (int p = 0; p < 8; p++) {                  // stage Q tile (32 KB)
        int c = p * 256 + t;
        int kb = c >> 7, r = c & 127;
        gload16(q + (size_t)(q0 + r) * D_MODEL + h * HDIM + kb * 8, &sQ[c * 8]);
    }
    if (t < 128) { sM[t] = -3e38f; sL[t] = 0.f; }
    const f32x4 fzero = {0.f, 0.f, 0.f, 0.f};
    f32x4 o[4][4];
#pragma unroll
    for (int i = 0; i < 4; i++)
#pragma unroll
        for (int j = 0; j < 4; j++) o[i][j] = fzero;
    asm volatile("s_waitcnt vmcnt(0)" ::: "memory");
    __syncthreads();

    const float scale = 0.08838834764831845f;      // 1/sqrt(128)

    for (int kt = 0; kt <= qt; kt++) {
        int k0 = kt * 128;
#pragma unroll
        for (int p = 0; p < 8; p++) {
            int c = p * 256 + t;
            int kb = c >> 7, r = c & 127;
            gload16(k + (size_t)(k0 + r) * D_MODEL + h * HDIM + kb * 8, &sK[c * 8]);
            gload16(vt + (size_t)(h * HDIM + r) * SEQ + k0 + kb * 8, &sV[c * 8]);
        }
        asm volatile("s_waitcnt vmcnt(0)" ::: "memory");
        __syncthreads();                            // B1

        // scores = Q @ K^T
        f32x4 sc[4][4];
#pragma unroll
        for (int i = 0; i < 4; i++)
#pragma unroll
            for (int j = 0; j < 4; j++) sc[i][j] = fzero;
#pragma unroll
        for (int kk = 0; kk < 4; kk++) {
            bf16x8 af[4], bfv[4];
#pragma unroll
            for (int i = 0; i < 4; i++)
                af[i] = *(const bf16x8*)&sQ[(kk * 4 + quad) * 1024 + (wr * 64 + i * 16 + l16) * 8];
#pragma unroll
            for (int j = 0; j < 4; j++)
                bfv[j] = *(const bf16x8*)&sK[(kk * 4 + quad) * 1024 + (wc * 64 + j * 16 + l16) * 8];
#pragma unroll
            for (int i = 0; i < 4; i++)
#pragma unroll
                for (int j = 0; j < 4; j++)
                    sc[i][j] = MFMA16(af[i], bfv[j], sc[i][j]);
        }

        // scale + causal mask + per-row max (this wave-half's 64 cols)
        float rmax[4][4];
#pragma unroll
        for (int i = 0; i < 4; i++)
#pragma unroll
            for (int r = 0; r < 4; r++) {
                int qrow = q0 + wr * 64 + i * 16 + quad * 4 + r;
                float mx = -3e38f;
#pragma unroll
                for (int j = 0; j < 4; j++) {
                    int kcol = k0 + wc * 64 + j * 16 + l16;
                    float v = sc[i][j][r] * scale;
                    v = (kcol <= qrow) ? v : -3e38f;
                    sc[i][j][r] = v;
                    mx = fmaxf(mx, v);
                }
#pragma unroll
                for (int dlt = 1; dlt < 16; dlt <<= 1)
                    mx = fmaxf(mx, __shfl_xor(mx, dlt, 64));
                rmax[i][r] = mx;
            }
        if (l16 == 0) {
#pragma unroll
            for (int i = 0; i < 4; i++)
#pragma unroll
                for (int r = 0; r < 4; r++)
                    sRed[wc][wr * 64 + i * 16 + quad * 4 + r] = rmax[i][r];
        }
        __syncthreads();                            // B2

        float alpha[4][4], rsum[4][4], mnv[4][4];
#pragma unroll
        for (int i = 0; i < 4; i++)
#pragma unroll
            for (int r = 0; r < 4; r++) {
                int row = wr * 64 + i * 16 + quad * 4 + r;
                float tm = fmaxf(rmax[i][r], sRed[1 - wc][row]);
                float mo = sM[row];
                float mn = fmaxf(mo, tm);
                mnv[i][r] = mn;
                alpha[i][r] = __expf(mo - mn);
                float s = 0.f;
#pragma unroll
                for (int j = 0; j < 4; j++) {
                    float pv = __expf(sc[i][j][r] - mn);
                    sc[i][j][r] = pv;
                    s += pv;
                }
#pragma unroll
                for (int dlt = 1; dlt < 16; dlt <<= 1)
                    s += __shfl_xor(s, dlt, 64);
                rsum[i][r] = s;
            }
        __syncthreads();                            // B3 (all max reads done)
        if (l16 == 0) {
#pragma unroll
            for (int i = 0; i < 4; i++)
#pragma unroll
                for (int r = 0; r < 4; r++)
                    sRed[wc][wr * 64 + i * 16 + quad * 4 + r] = rsum[i][r];
        }
        // write P (bf16) into sK region, blocked layout [kb][row][8]
#pragma unroll
        for (int i = 0; i < 4; i++)
#pragma unroll
            for (int j = 0; j < 4; j++)
#pragma unroll
                for (int r = 0; r < 4; r++) {
                    int row = wr * 64 + i * 16 + quad * 4 + r;
                    int col = wc * 64 + j * 16 + l16;
                    sK[(col >> 3) * 1024 + row * 8 + (col & 7)] = f2bf(sc[i][j][r]);
                }
        // rescale O
#pragma unroll
        for (int i = 0; i < 4; i++)
#pragma unroll
            for (int j = 0; j < 4; j++)
#pragma unroll
                for (int r = 0; r < 4; r++) o[i][j][r] *= alpha[i][r];
        __syncthreads();                            // B4 (P + sums visible)
        if (wc == 0 && l16 == 0) {
#pragma unroll
            for (int i = 0; i < 4; i++)
#pragma unroll
                for (int r = 0; r < 4; r++) {
                    int row = wr * 64 + i * 16 + quad * 4 + r;
                    float tot = rsum[i][r] + sRed[1][row];
                    sM[row] = mnv[i][r];
                    sL[row] = alpha[i][r] * sL[row] + tot;
                }
        }
        // O += P @ V^T-tile
#pragma unroll
        for (int kk = 0; kk < 4; kk++) {
            bf16x8 af[4], bfv[4];
#pragma unroll
            for (int i = 0; i < 4; i++)
                af[i] = *(const bf16x8*)&sK[(kk * 4 + quad) * 1024 + (wr * 64 + i * 16 + l16) * 8];
#pragma unroll
            for (int j = 0; j < 4; j++)
                bfv[j] = *(const bf16x8*)&sV[(kk * 4 + quad) * 1024 + (wc * 64 + j * 16 + l16) * 8];
#pragma unroll
            for (int i = 0; i < 4; i++)
#pragma unroll
                for (int j = 0; j < 4; j++)
                    o[i][j] = MFMA16(af[i], bfv[j], o[i][j]);
        }
        __syncthreads();                            // B5
    }

#pragma unroll
    for (int i = 0; i < 4; i++)
#pragma unroll
        for (int r = 0; r < 4; r++) {
            int row = wr * 64 + i * 16 + quad * 4 + r;
            float inv = 1.f / sL[row];
#pragma unroll
            for (int j = 0; j < 4; j++) {
                int n = h * HDIM + wc * 64 + j * 16 + l16;
                ctx[(size_t)(q0 + row) * D_MODEL + n] = f2bf(o[i][j][r] * inv);
            }
        }
}

// ---------- host launch ----------
extern "C" void kernel_launch(void* const* d_in, const int* in_sizes, int n_in,
                              void* d_out, int out_size, void* d_ws, size_t ws_size,
                              hipStream_t stream)
{
    const float* x    = (const float*)d_in[0];
    const float* fcos = (const float*)d_in[2];
    const float* fsin = (const float*)d_in[3];
    const float* wq   = (const float*)d_in[4];
    const float* wk   = (const float*)d_in[5];
    const float* wv   = (const float*)d_in[6];
    const float* wo   = (const float*)d_in[7];
    const float* w1   = (const float*)d_in[8];
    const float* w2   = (const float*)d_in[9];
    const float* w3   = (const float*)d_in[10];
    const float* anw  = (const float*)d_in[11];
    const float* fnw  = (const float*)d_in[12];
    float* out = (float*)d_out;

    const size_t SD = (size_t)SEQ * D_MODEL;   // 4 Mi elems
    const size_t SI = (size_t)SEQ * IDIM;      // 16 Mi elems

    char* p = (char*)d_ws;
    auto alloc = [&](size_t bytes) { char* r = p; p += (bytes + 255) & ~(size_t)255; return r; };
    u16*   nx   = (u16*)  alloc(SD * 2);
    u16*   qb   = (u16*)  alloc(SD * 2);
    u16*   kb   = (u16*)  alloc(SD * 2);
    u16*   vb   = (u16*)  alloc(SD * 2);
    u16*   vtb  = (u16*)  alloc(SD * 2);
    u16*   ctxb = (u16*)  alloc(SD * 2);
    float* x1   = (float*)alloc(SD * 4);
    u16*   nx2  = (u16*)  alloc(SD * 2);
    u16*   hb   = (u16*)  alloc(SI * 2);
    u16*   wqT  = (u16*)  alloc(SD * 2);
    u16*   wkT  = (u16*)  alloc(SD * 2);
    u16*   wvT  = (u16*)  alloc(SD * 2);
    u16*   woT  = (u16*)  alloc(SD * 2);
    u16*   w1T  = (u16*)  alloc(SI * 2);
    u16*   w3T  = (u16*)  alloc(SI * 2);
    u16*   w2T  = (u16*)  alloc(SI * 2);

    dim3 blk(256);

    rmsnorm_kernel<<<SEQ, blk, 0, stream>>>(x, anw, nx);
    tcvt_kernel<<<dim3(64, 64),  blk, 0, stream>>>(wq, wqT, D_MODEL, D_MODEL);
    tcvt_kernel<<<dim3(64, 64),  blk, 0, stream>>>(wk, wkT, D_MODEL, D_MODEL);
    tcvt_kernel<<<dim3(64, 64),  blk, 0, stream>>>(wv, wvT, D_MODEL, D_MODEL);
    tcvt_kernel<<<dim3(64, 64),  blk, 0, stream>>>(wo, woT, D_MODEL, D_MODEL);
    tcvt_kernel<<<dim3(256, 64), blk, 0, stream>>>(w1, w1T, D_MODEL, IDIM);
    tcvt_kernel<<<dim3(256, 64), blk, 0, stream>>>(w3, w3T, D_MODEL, IDIM);
    tcvt_kernel<<<dim3(64, 256), blk, 0, stream>>>(w2, w2T, IDIM, D_MODEL);

    gemm_bt<0><<<dim3(16, 16), blk, 0, stream>>>(nx, wqT, nullptr, nullptr, qb, SEQ, D_MODEL, D_MODEL);
    gemm_bt<0><<<dim3(16, 16), blk, 0, stream>>>(nx, wkT, nullptr, nullptr, kb, SEQ, D_MODEL, D_MODEL);
    gemm_bt<0><<<dim3(16, 16), blk, 0, stream>>>(nx, wvT, nullptr, nullptr, vb, SEQ, D_MODEL, D_MODEL);

    rope_kernel<<<SEQ, blk, 0, stream>>>(qb, kb, fcos, fsin);
    tbf16_kernel<<<dim3(64, 64), blk, 0, stream>>>(vb, vtb, SEQ, D_MODEL);

    attn_kernel<<<dim3(16, 16), blk, 0, stream>>>(qb, kb, vtb, ctxb);

    gemm_bt<1><<<dim3(16, 16), blk, 0, stream>>>(ctxb, woT, x, x1, nullptr, SEQ, D_MODEL, D_MODEL);
    rmsnorm_kernel<<<SEQ, blk, 0, stream>>>(x1, fnw, nx2);
    gemm_ffn<<<dim3(64, 16), blk, 0, stream>>>(nx2, w1T, w3T, hb, SEQ, IDIM, D_MODEL);
    gemm_bt<1><<<dim3(16, 16), blk, 0, stream>>>(hb, w2T, x1, out, nullptr, SEQ, D_MODEL, IDIM);
}

// Round 4
// 1207.610 us; speedup vs baseline: 1.1903x; 1.1903x over previous
//
#include <hip/hip_runtime.h>

typedef unsigned short u16;
typedef __bf16 bf16_t;
typedef bf16_t bf16x8 __attribute__((ext_vector_type(8)));
typedef float f32x4 __attribute__((ext_vector_type(4)));

#define D_MODEL 2048
#define SEQ     2048
#define NHEAD   16
#define HDIM    128
#define IDIM    8192
#define QKV_LD  6144

// ---------- helpers ----------
__device__ __forceinline__ u16 f2bf(float f) {
    unsigned u = __float_as_uint(f);
    u += 0x7fffu + ((u >> 16) & 1u);           // RNE
    return (u16)(u >> 16);
}
__device__ __forceinline__ float bf2f(u16 u) {
    return __uint_as_float(((unsigned)u) << 16);
}
__device__ __forceinline__ void gload16(const void* g, void* l) {
    __builtin_amdgcn_global_load_lds(
        (const __attribute__((address_space(1))) unsigned int*)g,
        (__attribute__((address_space(3))) unsigned int*)l, 16, 0, 0);
}
#define MFMA16(a, b, c) __builtin_amdgcn_mfma_f32_16x16x32_bf16((a), (b), (c), 0, 0, 0)

// ---------- RMSNorm: fp32 in -> bf16 out ----------
__global__ __launch_bounds__(256) void rmsnorm_kernel(
    const float* __restrict__ x, const float* __restrict__ w, u16* __restrict__ out)
{
    int row = blockIdx.x, t = threadIdx.x;
    const float4* xr = (const float4*)(x + (size_t)row * D_MODEL);
    float4 a = xr[t * 2], b = xr[t * 2 + 1];
    float ss = a.x*a.x + a.y*a.y + a.z*a.z + a.w*a.w
             + b.x*b.x + b.y*b.y + b.z*b.z + b.w*b.w;
#pragma unroll
    for (int off = 32; off > 0; off >>= 1) ss += __shfl_down(ss, off, 64);
    __shared__ float red[4];
    __shared__ float sinv;
    if ((t & 63) == 0) red[t >> 6] = ss;
    __syncthreads();
    if (t == 0) sinv = rsqrtf((red[0] + red[1] + red[2] + red[3]) * (1.0f / D_MODEL) + 1e-5f);
    __syncthreads();
    float inv = sinv;
    const float4* w4 = (const float4*)w;
    float4 wa = w4[t * 2], wb = w4[t * 2 + 1];
    u16* o = out + (size_t)row * D_MODEL + t * 8;
    o[0] = f2bf(a.x * inv * wa.x); o[1] = f2bf(a.y * inv * wa.y);
    o[2] = f2bf(a.z * inv * wa.z); o[3] = f2bf(a.w * inv * wa.w);
    o[4] = f2bf(b.x * inv * wb.x); o[5] = f2bf(b.y * inv * wb.y);
    o[6] = f2bf(b.z * inv * wb.z); o[7] = f2bf(b.w * inv * wb.w);
}

// ---------- transpose + fp32->bf16 : src[R][C] -> dst[C][R] ----------
__global__ __launch_bounds__(256) void tcvt_kernel(
    const float* __restrict__ src, u16* __restrict__ dst, int R, int C)
{
    __shared__ float tile[32][33];
    int tx = threadIdx.x & 31, ty = threadIdx.x >> 5;
    int c = blockIdx.x * 32 + tx;
    int rb = blockIdx.y * 32;
#pragma unroll
    for (int i = 0; i < 32; i += 8)
        tile[ty + i][tx] = src[(size_t)(rb + ty + i) * C + c];
    __syncthreads();
    int dr = blockIdx.x * 32 + ty;
    int dc = rb + tx;
#pragma unroll
    for (int i = 0; i < 32; i += 8)
        dst[(size_t)(dr + i) * R + dc] = f2bf(tile[tx][ty + i]);
}

// ---------- bf16 transpose : src[R][C] (row stride ld) -> dst[C][R] ----------
__global__ __launch_bounds__(256) void tbf16_kernel(
    const u16* __restrict__ src, u16* __restrict__ dst, int R, int C, int ld)
{
    __shared__ u16 tile[32][34];
    int tx = threadIdx.x & 31, ty = threadIdx.x >> 5;
    int c = blockIdx.x * 32 + tx;
    int rb = blockIdx.y * 32;
#pragma unroll
    for (int i = 0; i < 32; i += 8)
        tile[ty + i][tx] = src[(size_t)(rb + ty + i) * ld + c];
    __syncthreads();
    int dr = blockIdx.x * 32 + ty;
    int dc = rb + tx;
#pragma unroll
    for (int i = 0; i < 32; i += 8)
        dst[(size_t)(dr + i) * R + dc] = tile[tx][ty + i];
}

// ---------- RoPE in-place on fused qkv buffer (q at col 0, k at col 2048) ----------
__global__ __launch_bounds__(256) void rope_kernel(
    u16* __restrict__ qkv, const float* __restrict__ fc, const float* __restrict__ fs)
{
    int s = blockIdx.x, t = threadIdx.x;
    const float* cr = fc + (size_t)s * HDIM;
    const float* sr = fs + (size_t)s * HDIM;
#pragma unroll
    for (int p = 0; p < 4; p++) {
        int pi = p * 256 + t;
        int h = pi >> 6, d = pi & 63;
        size_t base = (size_t)s * QKV_LD + h * HDIM + d;
        float c1 = cr[d], s1 = sr[d], c2 = cr[d + 64], s2 = sr[d + 64];
        float q1 = bf2f(qkv[base]), q2 = bf2f(qkv[base + 64]);
        qkv[base]      = f2bf(q1 * c1 - q2 * s1);
        qkv[base + 64] = f2bf(q2 * c2 + q1 * s2);
        size_t kb = base + 2048;
        float k1 = bf2f(qkv[kb]), k2 = bf2f(qkv[kb + 64]);
        qkv[kb]      = f2bf(k1 * c1 - k2 * s1);
        qkv[kb + 64] = f2bf(k2 * c2 + k1 * s2);
    }
}

// ---------- GEMM C = A @ Bt^T  (A:[M][lda] bf16, Bt:[N][ldb] bf16) ----------
// BM x 128 tile, 4 waves, BK=32, LDS blocked-K [kb][rows][8].
// blockIdx.z selects a K-slice of length K at offset z*K (split-K); grids
// without z use gridDim.z=1.
// EPI 0: bf16 store. EPI 1: outf = res + acc. EPI 2: bf16 silu(gate)*acc.
// EPI 3: f32 partial store at outf + z*M*N.
template <int BM, int EPI>
__global__ __launch_bounds__(256) void gemm_bt(
    const u16* __restrict__ A, const u16* __restrict__ Bt,
    const float* __restrict__ res, const u16* __restrict__ gate,
    float* __restrict__ outf, u16* __restrict__ outb,
    int M, int N, int K, int lda, int ldb)
{
    constexpr int WC = (BM == 128) ? 2 : 4;   // waves along N
    constexpr int MI = 4;                      // 16-row frags per wave
    constexpr int NJ = (BM == 128) ? 4 : 2;   // 16-col frags per wave
    constexpr int LA = (BM * 32) / (256 * 8); // A-chunks per thread (2 or 1)
    __shared__ __align__(16) u16 lA[BM * 32];
    __shared__ __align__(16) u16 lB[128 * 32];
    int t = threadIdx.x;
    int wave = t >> 6, lane = t & 63, quad = lane >> 4, l16 = lane & 15;
    int wr = wave / WC, wc = wave % WC;
    int m0 = blockIdx.y * BM, n0 = blockIdx.x * 128;
    int mb = wr * (MI * 16), nb = wc * (NJ * 16);
    int koff = blockIdx.z * K;

    f32x4 acc[MI][NJ];
    const f32x4 fzero = {0.f, 0.f, 0.f, 0.f};
#pragma unroll
    for (int i = 0; i < MI; i++)
#pragma unroll
        for (int j = 0; j < NJ; j++) acc[i][j] = fzero;

    const u16* gA[LA]; u16* lAp[LA];
#pragma unroll
    for (int l = 0; l < LA; l++) {
        int c = l * 256 + t;
        int kb = c / BM, row = c % BM;
        gA[l] = A + (size_t)(m0 + row) * lda + koff + kb * 8;
        lAp[l] = &lA[c * 8];
    }
    const u16* gB[2]; u16* lBp[2];
#pragma unroll
    for (int l = 0; l < 2; l++) {
        int c = l * 256 + t;
        int kb = c >> 7, row = c & 127;
        gB[l] = Bt + (size_t)(n0 + row) * ldb + koff + kb * 8;
        lBp[l] = &lB[c * 8];
    }

    for (int k0 = 0; k0 < K; k0 += 32) {
#pragma unroll
        for (int l = 0; l < LA; l++) gload16(gA[l] + k0, lAp[l]);
        gload16(gB[0] + k0, lBp[0]);
        gload16(gB[1] + k0, lBp[1]);
        asm volatile("s_waitcnt vmcnt(0)" ::: "memory");
        __syncthreads();
        bf16x8 af[MI], bfv[NJ];
#pragma unroll
        for (int i = 0; i < MI; i++)
            af[i] = *(const bf16x8*)&lA[quad * (BM * 8) + (mb + i * 16 + l16) * 8];
#pragma unroll
        for (int j = 0; j < NJ; j++)
            bfv[j] = *(const bf16x8*)&lB[quad * 1024 + (nb + j * 16 + l16) * 8];
#pragma unroll
        for (int i = 0; i < MI; i++)
#pragma unroll
            for (int j = 0; j < NJ; j++)
                acc[i][j] = MFMA16(af[i], bfv[j], acc[i][j]);
        __syncthreads();
    }

    float* po = (EPI == 3) ? outf + (size_t)blockIdx.z * M * N : outf;
#pragma unroll
    for (int i = 0; i < MI; i++)
#pragma unroll
        for (int j = 0; j < NJ; j++)
#pragma unroll
            for (int r = 0; r < 4; r++) {
                int m = m0 + mb + i * 16 + quad * 4 + r;
                int n = n0 + nb + j * 16 + l16;
                size_t idx = (size_t)m * N + n;
                float v = acc[i][j][r];
                if (EPI == 0) {
                    outb[idx] = f2bf(v);
                } else if (EPI == 1) {
                    outf[idx] = res[idx] + v;
                } else if (EPI == 2) {
                    float g = bf2f(gate[idx]);
                    outb[idx] = f2bf(g / (1.f + __expf(-g)) * v);
                } else {
                    po[idx] = v;
                }
            }
}

// ---------- split-K reduce: out = x1 + sum_z part[z] ----------
__global__ __launch_bounds__(256) void reduce4_kernel(
    const float* __restrict__ x1, const float* __restrict__ part, float* __restrict__ out)
{
    size_t i = (size_t)blockIdx.x * 256 + threadIdx.x;   // float4 index
    const size_t NQ = (size_t)SEQ * D_MODEL / 4;
    float4 a = ((const float4*)x1)[i];
#pragma unroll
    for (int z = 0; z < 4; z++) {
        float4 pv = ((const float4*)(part + (size_t)z * SEQ * D_MODEL))[i];
        a.x += pv.x; a.y += pv.y; a.z += pv.z; a.w += pv.w;
    }
    ((float4*)out)[i] = a;
}

// ---------- flash attention: one block per (q-tile 128, head) ----------
// q rows at qb + s*QKV_LD + h*128 ; k rows at kb + s*QKV_LD + h*128
__global__ __launch_bounds__(256, 1) void attn_kernel(
    const u16* __restrict__ q, const u16* __restrict__ k,
    const u16* __restrict__ vt, u16* __restrict__ ctx)
{
    __shared__ __align__(16) u16 sQ[128 * 128];
    __shared__ __align__(16) u16 sK[128 * 128];   // reused as P after QK^T
    __shared__ __align__(16) u16 sV[128 * 128];   // V^T tile [d][s]
    __shared__ float sRed[2][128];
    __shared__ float sM[128];
    __shared__ float sL[128];

    int t = threadIdx.x;
    int wave = t >> 6, lane = t & 63, quad = lane >> 4, l16 = lane & 15;
    int wr = wave >> 1, wc = wave & 1;
    int h = blockIdx.y, qt = blockIdx.x;
    int q0 = qt * 128;

#pragma unroll
    for (int p = 0; p < 8; p++) {                  // stage Q tile (32 KB)
        int c = p * 256 + t;
        int kb = c >> 7, r = c & 127;
        gload16(q + (size_t)(q0 + r) * QKV_LD + h * HDIM + kb * 8, &sQ[c * 8]);
    }
    if (t < 128) { sM[t] = -3e38f; sL[t] = 0.f; }
    const f32x4 fzero = {0.f, 0.f, 0.f, 0.f};
    f32x4 o[4][4];
#pragma unroll
    for (int i = 0; i < 4; i++)
#pragma unroll
        for (int j = 0; j < 4; j++) o[i][j] = fzero;
    asm volatile("s_waitcnt vmcnt(0)" ::: "memory");
    __syncthreads();

    const float scale = 0.08838834764831845f;      // 1/sqrt(128)

    for (int kt = 0; kt <= qt; kt++) {
        int k0 = kt * 128;
#pragma unroll
        for (int p = 0; p < 8; p++) {
            int c = p * 256 + t;
            int kb = c >> 7, r = c & 127;
            gload16(k + (size_t)(k0 + r) * QKV_LD + h * HDIM + kb * 8, &sK[c * 8]);
            gload16(vt + (size_t)(h * HDIM + r) * SEQ + k0 + kb * 8, &sV[c * 8]);
        }
        asm volatile("s_waitcnt vmcnt(0)" ::: "memory");
        __syncthreads();                            // B1

        // scores = Q @ K^T
        f32x4 sc[4][4];
#pragma unroll
        for (int i = 0; i < 4; i++)
#pragma unroll
            for (int j = 0; j < 4; j++) sc[i][j] = fzero;
#pragma unroll
        for (int kk = 0; kk < 4; kk++) {
            bf16x8 af[4], bfv[4];
#pragma unroll
            for (int i = 0; i < 4; i++)
                af[i] = *(const bf16x8*)&sQ[(kk * 4 + quad) * 1024 + (wr * 64 + i * 16 + l16) * 8];
#pragma unroll
            for (int j = 0; j < 4; j++)
                bfv[j] = *(const bf16x8*)&sK[(kk * 4 + quad) * 1024 + (wc * 64 + j * 16 + l16) * 8];
#pragma unroll
            for (int i = 0; i < 4; i++)
#pragma unroll
                for (int j = 0; j < 4; j++)
                    sc[i][j] = MFMA16(af[i], bfv[j], sc[i][j]);
        }

        // scale + causal mask + per-row max (this wave-half's 64 cols)
        float rmax[4][4];
#pragma unroll
        for (int i = 0; i < 4; i++)
#pragma unroll
            for (int r = 0; r < 4; r++) {
                int qrow = q0 + wr * 64 + i * 16 + quad * 4 + r;
                float mx = -3e38f;
#pragma unroll
                for (int j = 0; j < 4; j++) {
                    int kcol = k0 + wc * 64 + j * 16 + l16;
                    float v = sc[i][j][r] * scale;
                    v = (kcol <= qrow) ? v : -3e38f;
                    sc[i][j][r] = v;
                    mx = fmaxf(mx, v);
                }
#pragma unroll
                for (int dlt = 1; dlt < 16; dlt <<= 1)
                    mx = fmaxf(mx, __shfl_xor(mx, dlt, 64));
                rmax[i][r] = mx;
            }
        if (l16 == 0) {
#pragma unroll
            for (int i = 0; i < 4; i++)
#pragma unroll
                for (int r = 0; r < 4; r++)
                    sRed[wc][wr * 64 + i * 16 + quad * 4 + r] = rmax[i][r];
        }
        __syncthreads();                            // B2

        float alpha[4][4], rsum[4][4], mnv[4][4];
#pragma unroll
        for (int i = 0; i < 4; i++)
#pragma unroll
            for (int r = 0; r < 4; r++) {
                int row = wr * 64 + i * 16 + quad * 4 + r;
                float tm = fmaxf(rmax[i][r], sRed[1 - wc][row]);
                float mo = sM[row];
                float mn = fmaxf(mo, tm);
                mnv[i][r] = mn;
                alpha[i][r] = __expf(mo - mn);
                float s = 0.f;
#pragma unroll
                for (int j = 0; j < 4; j++) {
                    float pv = __expf(sc[i][j][r] - mn);
                    sc[i][j][r] = pv;
                    s += pv;
                }
#pragma unroll
                for (int dlt = 1; dlt < 16; dlt <<= 1)
                    s += __shfl_xor(s, dlt, 64);
                rsum[i][r] = s;
            }
        __syncthreads();                            // B3 (all max reads done)
        if (l16 == 0) {
#pragma unroll
            for (int i = 0; i < 4; i++)
#pragma unroll
                for (int r = 0; r < 4; r++)
                    sRed[wc][wr * 64 + i * 16 + quad * 4 + r] = rsum[i][r];
        }
        // write P (bf16) into sK region, blocked layout [kb][row][8]
#pragma unroll
        for (int i = 0; i < 4; i++)
#pragma unroll
            for (int j = 0; j < 4; j++)
#pragma unroll
                for (int r = 0; r < 4; r++) {
                    int row = wr * 64 + i * 16 + quad * 4 + r;
                    int col = wc * 64 + j * 16 + l16;
                    sK[(col >> 3) * 1024 + row * 8 + (col & 7)] = f2bf(sc[i][j][r]);
                }
        // rescale O
#pragma unroll
        for (int i = 0; i < 4; i++)
#pragma unroll
            for (int j = 0; j < 4; j++)
#pragma unroll
                for (int r = 0; r < 4; r++) o[i][j][r] *= alpha[i][r];
        __syncthreads();                            // B4 (P + sums visible)
        if (wc == 0 && l16 == 0) {
#pragma unroll
            for (int i = 0; i < 4; i++)
#pragma unroll
                for (int r = 0; r < 4; r++) {
                    int row = wr * 64 + i * 16 + quad * 4 + r;
                    float tot = rsum[i][r] + sRed[1][row];
                    sM[row] = mnv[i][r];
                    sL[row] = alpha[i][r] * sL[row] + tot;
                }
        }
        // O += P @ V^T-tile
#pragma unroll
        for (int kk = 0; kk < 4; kk++) {
            bf16x8 af[4], bfv[4];
#pragma unroll
            for (int i = 0; i < 4; i++)
                af[i] = *(const bf16x8*)&sK[(kk * 4 + quad) * 1024 + (wr * 64 + i * 16 + l16) * 8];
#pragma unroll
            for (int j = 0; j < 4; j++)
                bfv[j] = *(const bf16x8*)&sV[(kk * 4 + quad) * 1024 + (wc * 64 + j * 16 + l16) * 8];
#pragma unroll
            for (int i = 0; i < 4; i++)
#pragma unroll
                for (int j = 0; j < 4; j++)
                    o[i][j] = MFMA16(af[i], bfv[j], o[i][j]);
        }
        __syncthreads();                            // B5
    }

#pragma unroll
    for (int i = 0; i < 4; i++)
#pragma unroll
        for (int r = 0; r < 4; r++) {
            int row = wr * 64 + i * 16 + quad * 4 + r;
            float inv = 1.f / sL[row];
#pragma unroll
            for (int j = 0; j < 4; j++) {
                int n = h * HDIM + wc * 64 + j * 16 + l16;
                ctx[(size_t)(q0 + row) * D_MODEL + n] = f2bf(o[i][j][r] * inv);
            }
        }
}

// ---------- host launch ----------
extern "C" void kernel_launch(void* const* d_in, const int* in_sizes, int n_in,
                              void* d_out, int out_size, void* d_ws, size_t ws_size,
                              hipStream_t stream)
{
    const float* x    = (const float*)d_in[0];
    const float* fcos = (const float*)d_in[2];
    const float* fsin = (const float*)d_in[3];
    const float* wq   = (const float*)d_in[4];
    const float* wk   = (const float*)d_in[5];
    const float* wv   = (const float*)d_in[6];
    const float* wo   = (const float*)d_in[7];
    const float* w1   = (const float*)d_in[8];
    const float* w2   = (const float*)d_in[9];
    const float* w3   = (const float*)d_in[10];
    const float* anw  = (const float*)d_in[11];
    const float* fnw  = (const float*)d_in[12];
    float* out = (float*)d_out;

    const size_t MB = 1024 * 1024;
    char* base = (char*)d_ws;
    // layout (MB offsets):
    u16*   qkvT = (u16*)  (base + 0);          // 24 MB  [6144][2048] bf16
    u16*   woT  = (u16*)  (base + 24 * MB);    //  8 MB
    u16*   w1T  = (u16*)  (base + 32 * MB);    // 32 MB
    u16*   w3T  = (u16*)  (base + 64 * MB);    // 32 MB
    u16*   w2T  = (u16*)  (base + 96 * MB);    // 32 MB
    u16*   nx   = (u16*)  (base + 128 * MB);   //  8 MB
    u16*   qkv  = (u16*)  (base + 136 * MB);   // 24 MB  [2048][6144] bf16
    u16*   vtb  = (u16*)  (base + 160 * MB);   //  8 MB
    u16*   ctxb = (u16*)  (base + 168 * MB);   //  8 MB
    float* x1   = (float*)(base + 176 * MB);   // 16 MB
    u16*   nx2  = (u16*)  (base + 192 * MB);   //  8 MB
    u16*   h1b  = (u16*)  (base + 200 * MB);   // 32 MB
    u16*   hb   = (u16*)  (base + 232 * MB);   // 32 MB -> total 264 MB
    // split-K partials (64 MB f32) alias the weight-T region [0,64) MB,
    // which is dead by the time the w2 GEMM runs (stream-ordered).
    float* part = (float*)(base + 0);

    dim3 blk(256);

    rmsnorm_kernel<<<SEQ, blk, 0, stream>>>(x, anw, nx);
    tcvt_kernel<<<dim3(64, 64),  blk, 0, stream>>>(wq, qkvT,                     D_MODEL, D_MODEL);
    tcvt_kernel<<<dim3(64, 64),  blk, 0, stream>>>(wk, qkvT + 2048 * 2048,       D_MODEL, D_MODEL);
    tcvt_kernel<<<dim3(64, 64),  blk, 0, stream>>>(wv, qkvT + (size_t)4096 * 2048, D_MODEL, D_MODEL);
    tcvt_kernel<<<dim3(64, 64),  blk, 0, stream>>>(wo, woT, D_MODEL, D_MODEL);
    tcvt_kernel<<<dim3(256, 64), blk, 0, stream>>>(w1, w1T, D_MODEL, IDIM);
    tcvt_kernel<<<dim3(256, 64), blk, 0, stream>>>(w3, w3T, D_MODEL, IDIM);
    tcvt_kernel<<<dim3(64, 256), blk, 0, stream>>>(w2, w2T, IDIM, D_MODEL);

    // fused QKV projection: [2048][6144]
    gemm_bt<128, 0><<<dim3(48, 16), blk, 0, stream>>>(
        nx, qkvT, nullptr, nullptr, nullptr, qkv, SEQ, QKV_LD, D_MODEL, D_MODEL, D_MODEL);

    rope_kernel<<<SEQ, blk, 0, stream>>>(qkv, fcos, fsin);
    tbf16_kernel<<<dim3(64, 64), blk, 0, stream>>>(qkv + 4096, vtb, SEQ, D_MODEL, QKV_LD);

    attn_kernel<<<dim3(16, 16), blk, 0, stream>>>(qkv, qkv + 2048, vtb, ctxb);

    // wo projection + residual (BM=64 -> 512 blocks)
    gemm_bt<64, 1><<<dim3(16, 32), blk, 0, stream>>>(
        ctxb, woT, x, nullptr, x1, nullptr, SEQ, D_MODEL, D_MODEL, D_MODEL, D_MODEL);

    rmsnorm_kernel<<<SEQ, blk, 0, stream>>>(x1, fnw, nx2);

    // FFN: h1 = nx2@w1T ; h = silu(h1) * (nx2@w3T)
    gemm_bt<128, 0><<<dim3(64, 16), blk, 0, stream>>>(
        nx2, w1T, nullptr, nullptr, nullptr, h1b, SEQ, IDIM, D_MODEL, D_MODEL, D_MODEL);
    gemm_bt<128, 2><<<dim3(64, 16), blk, 0, stream>>>(
        nx2, w3T, nullptr, h1b, nullptr, hb, SEQ, IDIM, D_MODEL, D_MODEL, D_MODEL);

    // w2 GEMM split-K x4, then reduce + residual
    gemm_bt<128, 3><<<dim3(16, 16, 4), blk, 0, stream>>>(
        hb, w2T, nullptr, nullptr, part, nullptr, SEQ, D_MODEL, 2048, IDIM, IDIM);
    reduce4_kernel<<<dim3(4096), blk, 0, stream>>>(x1, part, out);
}

// Round 5
// 845.786 us; speedup vs baseline: 1.6994x; 1.4278x over previous
//
#include <hip/hip_runtime.h>

typedef unsigned short u16;
typedef __bf16 bf16_t;
typedef bf16_t bf16x8 __attribute__((ext_vector_type(8)));
typedef float f32x4 __attribute__((ext_vector_type(4)));

#define D_MODEL 2048
#define SEQ     2048
#define NHEAD   16
#define HDIM    128
#define IDIM    8192
#define QKV_LD  6144

// ---------- helpers ----------
__device__ __forceinline__ u16 f2bf(float f) {
    unsigned u = __float_as_uint(f);
    u += 0x7fffu + ((u >> 16) & 1u);           // RNE
    return (u16)(u >> 16);
}
__device__ __forceinline__ float bf2f(u16 u) {
    return __uint_as_float(((unsigned)u) << 16);
}
__device__ __forceinline__ void gload16(const void* g, void* l) {
    __builtin_amdgcn_global_load_lds(
        (const __attribute__((address_space(1))) unsigned int*)g,
        (__attribute__((address_space(3))) unsigned int*)l, 16, 0, 0);
}
#define MFMA16(a, b, c) __builtin_amdgcn_mfma_f32_16x16x32_bf16((a), (b), (c), 0, 0, 0)

// ---------- RMSNorm: fp32 in -> bf16 out ----------
__global__ __launch_bounds__(256) void rmsnorm_kernel(
    const float* __restrict__ x, const float* __restrict__ w, u16* __restrict__ out)
{
    int row = blockIdx.x, t = threadIdx.x;
    const float4* xr = (const float4*)(x + (size_t)row * D_MODEL);
    float4 a = xr[t * 2], b = xr[t * 2 + 1];
    float ss = a.x*a.x + a.y*a.y + a.z*a.z + a.w*a.w
             + b.x*b.x + b.y*b.y + b.z*b.z + b.w*b.w;
#pragma unroll
    for (int off = 32; off > 0; off >>= 1) ss += __shfl_down(ss, off, 64);
    __shared__ float red[4];
    __shared__ float sinv;
    if ((t & 63) == 0) red[t >> 6] = ss;
    __syncthreads();
    if (t == 0) sinv = rsqrtf((red[0] + red[1] + red[2] + red[3]) * (1.0f / D_MODEL) + 1e-5f);
    __syncthreads();
    float inv = sinv;
    const float4* w4 = (const float4*)w;
    float4 wa = w4[t * 2], wb = w4[t * 2 + 1];
    u16* o = out + (size_t)row * D_MODEL + t * 8;
    o[0] = f2bf(a.x * inv * wa.x); o[1] = f2bf(a.y * inv * wa.y);
    o[2] = f2bf(a.z * inv * wa.z); o[3] = f2bf(a.w * inv * wa.w);
    o[4] = f2bf(b.x * inv * wb.x); o[5] = f2bf(b.y * inv * wb.y);
    o[6] = f2bf(b.z * inv * wb.z); o[7] = f2bf(b.w * inv * wb.w);
}

// ---------- transpose + fp32->bf16 : src[R][C] -> dst[C][R] ----------
__global__ __launch_bounds__(256) void tcvt_kernel(
    const float* __restrict__ src, u16* __restrict__ dst, int R, int C)
{
    __shared__ float tile[32][33];
    int tx = threadIdx.x & 31, ty = threadIdx.x >> 5;
    int c = blockIdx.x * 32 + tx;
    int rb = blockIdx.y * 32;
#pragma unroll
    for (int i = 0; i < 32; i += 8)
        tile[ty + i][tx] = src[(size_t)(rb + ty + i) * C + c];
    __syncthreads();
    int dr = blockIdx.x * 32 + ty;
    int dc = rb + tx;
#pragma unroll
    for (int i = 0; i < 32; i += 8)
        dst[(size_t)(dr + i) * R + dc] = f2bf(tile[tx][ty + i]);
}

// ---------- bf16 transpose : src[R][C] (row stride ld) -> dst[C][R] ----------
__global__ __launch_bounds__(256) void tbf16_kernel(
    const u16* __restrict__ src, u16* __restrict__ dst, int R, int C, int ld)
{
    __shared__ u16 tile[32][34];
    int tx = threadIdx.x & 31, ty = threadIdx.x >> 5;
    int c = blockIdx.x * 32 + tx;
    int rb = blockIdx.y * 32;
#pragma unroll
    for (int i = 0; i < 32; i += 8)
        tile[ty + i][tx] = src[(size_t)(rb + ty + i) * ld + c];
    __syncthreads();
    int dr = blockIdx.x * 32 + ty;
    int dc = rb + tx;
#pragma unroll
    for (int i = 0; i < 32; i += 8)
        dst[(size_t)(dr + i) * R + dc] = tile[tx][ty + i];
}

// ---------- RoPE in-place on fused qkv buffer (q at col 0, k at col 2048) ----------
__global__ __launch_bounds__(256) void rope_kernel(
    u16* __restrict__ qkv, const float* __restrict__ fc, const float* __restrict__ fs)
{
    int s = blockIdx.x, t = threadIdx.x;
    const float* cr = fc + (size_t)s * HDIM;
    const float* sr = fs + (size_t)s * HDIM;
#pragma unroll
    for (int p = 0; p < 4; p++) {
        int pi = p * 256 + t;
        int h = pi >> 6, d = pi & 63;
        size_t base = (size_t)s * QKV_LD + h * HDIM + d;
        float c1 = cr[d], s1 = sr[d], c2 = cr[d + 64], s2 = sr[d + 64];
        float q1 = bf2f(qkv[base]), q2 = bf2f(qkv[base + 64]);
        qkv[base]      = f2bf(q1 * c1 - q2 * s1);
        qkv[base + 64] = f2bf(q2 * c2 + q1 * s2);
        size_t kb = base + 2048;
        float k1 = bf2f(qkv[kb]), k2 = bf2f(qkv[kb + 64]);
        qkv[kb]      = f2bf(k1 * c1 - k2 * s1);
        qkv[kb + 64] = f2bf(k2 * c2 + k1 * s2);
    }
}

// ---------- GEMM C = A @ Bt^T  (A:[M][lda] bf16, Bt:[N][ldb] bf16) ----------
// BM x 128 tile, 4 waves, BK=32.
// Staging: 4 lanes per 64B row (coalesced full lines); LDS [row][32] with
// chunk slot XOR-swizzled by ((row>>1)&3) to keep ds_read_b128 at 2-way.
// EPI 0: bf16 store. EPI 1: outf = res + acc. EPI 2: bf16 silu(gate)*acc.
// EPI 3: f32 partial store at outf + z*M*N (split-K via blockIdx.z).
template <int BM, int EPI>
__global__ __launch_bounds__(256, 3) void gemm_bt(
    const u16* __restrict__ A, const u16* __restrict__ Bt,
    const float* __restrict__ res, const u16* __restrict__ gate,
    float* __restrict__ outf, u16* __restrict__ outb,
    int M, int N, int K, int lda, int ldb)
{
    constexpr int WC = (BM == 128) ? 2 : 4;   // waves along N
    constexpr int MI = 4;                      // 16-row frags per wave
    constexpr int NJ = (BM == 128) ? 4 : 2;   // 16-col frags per wave
    constexpr int LA = BM / 64;                // A staging passes (64 rows each)
    __shared__ __align__(16) u16 lA[BM * 32];
    __shared__ __align__(16) u16 lB[128 * 32];
    int t = threadIdx.x;
    int wave = t >> 6, lane = t & 63, quad = lane >> 4, l16 = lane & 15;
    int wr = wave / WC, wc = wave % WC;
    int m0 = blockIdx.y * BM, n0 = blockIdx.x * 128;
    int mb = wr * (MI * 16), nb = wc * (NJ * 16);
    int koff = blockIdx.z * K;

    f32x4 acc[MI][NJ];
    const f32x4 fzero = {0.f, 0.f, 0.f, 0.f};
#pragma unroll
    for (int i = 0; i < MI; i++)
#pragma unroll
        for (int j = 0; j < NJ; j++) acc[i][j] = fzero;

    // staging: thread t covers row (pass*64 + t/4), 16B chunk slot (t&3),
    // global chunk = slot ^ ((row>>1)&3)  (same 64B line, swizzled order)
    const u16* gA[LA]; u16* lAp[LA];
#pragma unroll
    for (int l = 0; l < LA; l++) {
        int row = l * 64 + (t >> 2);
        int gch = (t & 3) ^ ((row >> 1) & 3);
        gA[l] = A + (size_t)(m0 + row) * lda + koff + gch * 8;
        lAp[l] = &lA[(l * 256 + t) * 8];
    }
    const u16* gB[2]; u16* lBp[2];
#pragma unroll
    for (int l = 0; l < 2; l++) {
        int row = l * 64 + (t >> 2);
        int gch = (t & 3) ^ ((row >> 1) & 3);
        gB[l] = Bt + (size_t)(n0 + row) * ldb + koff + gch * 8;
        lBp[l] = &lB[(l * 256 + t) * 8];
    }
    int fslot = (quad ^ ((l16 >> 1) & 3)) * 8;   // frag-read swizzled chunk

    for (int k0 = 0; k0 < K; k0 += 32) {
#pragma unroll
        for (int l = 0; l < LA; l++) gload16(gA[l] + k0, lAp[l]);
        gload16(gB[0] + k0, lBp[0]);
        gload16(gB[1] + k0, lBp[1]);
        asm volatile("s_waitcnt vmcnt(0)" ::: "memory");
        __syncthreads();
        bf16x8 af[MI], bfv[NJ];
#pragma unroll
        for (int i = 0; i < MI; i++)
            af[i] = *(const bf16x8*)&lA[(mb + i * 16 + l16) * 32 + fslot];
#pragma unroll
        for (int j = 0; j < NJ; j++)
            bfv[j] = *(const bf16x8*)&lB[(nb + j * 16 + l16) * 32 + fslot];
#pragma unroll
        for (int i = 0; i < MI; i++)
#pragma unroll
            for (int j = 0; j < NJ; j++)
                acc[i][j] = MFMA16(af[i], bfv[j], acc[i][j]);
        __syncthreads();
    }

    float* po = (EPI == 3) ? outf + (size_t)blockIdx.z * M * N : outf;
#pragma unroll
    for (int i = 0; i < MI; i++)
#pragma unroll
        for (int j = 0; j < NJ; j++)
#pragma unroll
            for (int r = 0; r < 4; r++) {
                int m = m0 + mb + i * 16 + quad * 4 + r;
                int n = n0 + nb + j * 16 + l16;
                size_t idx = (size_t)m * N + n;
                float v = acc[i][j][r];
                if (EPI == 0) {
                    outb[idx] = f2bf(v);
                } else if (EPI == 1) {
                    outf[idx] = res[idx] + v;
                } else if (EPI == 2) {
                    float g = bf2f(gate[idx]);
                    outb[idx] = f2bf(g / (1.f + __expf(-g)) * v);
                } else {
                    po[idx] = v;
                }
            }
}

// ---------- split-K reduce: out = x1 + sum_z part[z] ----------
__global__ __launch_bounds__(256) void reduce4_kernel(
    const float* __restrict__ x1, const float* __restrict__ part, float* __restrict__ out)
{
    size_t i = (size_t)blockIdx.x * 256 + threadIdx.x;   // float4 index
    float4 a = ((const float4*)x1)[i];
#pragma unroll
    for (int z = 0; z < 4; z++) {
        float4 pv = ((const float4*)(part + (size_t)z * SEQ * D_MODEL))[i];
        a.x += pv.x; a.y += pv.y; a.z += pv.z; a.w += pv.w;
    }
    ((float4*)out)[i] = a;
}

// ---------- flash attention: one block per (q-tile 128, head) ----------
// Tiles staged row-major [row][128 cols], chunk XOR-swizzled by (row&7).
__global__ __launch_bounds__(256, 1) void attn_kernel(
    const u16* __restrict__ q, const u16* __restrict__ k,
    const u16* __restrict__ vt, u16* __restrict__ ctx)
{
    __shared__ __align__(16) u16 sQ[128 * 128];
    __shared__ __align__(16) u16 sK[128 * 128];   // reused as P after QK^T
    __shared__ __align__(16) u16 sV[128 * 128];   // V^T tile [d][s]
    __shared__ float sRed[2][128];
    __shared__ float sM[128];
    __shared__ float sL[128];

    int t = threadIdx.x;
    int wave = t >> 6, lane = t & 63, quad = lane >> 4, l16 = lane & 15;
    int wr = wave >> 1, wc = wave & 1;
    int h = blockIdx.y, qt = blockIdx.x;
    int q0 = qt * 128;
    int srow = t >> 4, schunk = t & 15;           // staging: 16 lanes per 256B row

#pragma unroll
    for (int p = 0; p < 8; p++) {                  // stage Q tile (32 KB)
        int r = p * 16 + srow;
        int gc = schunk ^ (r & 7);
        gload16(q + (size_t)(q0 + r) * QKV_LD + h * HDIM + gc * 8, &sQ[p * 2048 + t * 8]);
    }
    if (t < 128) { sM[t] = -3e38f; sL[t] = 0.f; }
    const f32x4 fzero = {0.f, 0.f, 0.f, 0.f};
    f32x4 o[4][4];
#pragma unroll
    for (int i = 0; i < 4; i++)
#pragma unroll
        for (int j = 0; j < 4; j++) o[i][j] = fzero;
    asm volatile("s_waitcnt vmcnt(0)" ::: "memory");
    __syncthreads();

    const float scale = 0.08838834764831845f;      // 1/sqrt(128)
    int fsw = l16 & 7;                             // frag-read swizzle key

    for (int kt = 0; kt <= qt; kt++) {
        int k0 = kt * 128;
#pragma unroll
        for (int p = 0; p < 8; p++) {
            int r = p * 16 + srow;
            int gc = schunk ^ (r & 7);
            gload16(k + (size_t)(k0 + r) * QKV_LD + h * HDIM + gc * 8, &sK[p * 2048 + t * 8]);
            gload16(vt + (size_t)(h * HDIM + r) * SEQ + k0 + gc * 8, &sV[p * 2048 + t * 8]);
        }
        asm volatile("s_waitcnt vmcnt(0)" ::: "memory");
        __syncthreads();                            // B1

        // scores = Q @ K^T
        f32x4 sc[4][4];
#pragma unroll
        for (int i = 0; i < 4; i++)
#pragma unroll
            for (int j = 0; j < 4; j++) sc[i][j] = fzero;
#pragma unroll
        for (int kk = 0; kk < 4; kk++) {
            int cs = ((kk * 4 + quad) ^ fsw) * 8;
            bf16x8 af[4], bfv[4];
#pragma unroll
            for (int i = 0; i < 4; i++)
                af[i] = *(const bf16x8*)&sQ[(wr * 64 + i * 16 + l16) * 128 + cs];
#pragma unroll
            for (int j = 0; j < 4; j++)
                bfv[j] = *(const bf16x8*)&sK[(wc * 64 + j * 16 + l16) * 128 + cs];
#pragma unroll
            for (int i = 0; i < 4; i++)
#pragma unroll
                for (int j = 0; j < 4; j++)
                    sc[i][j] = MFMA16(af[i], bfv[j], sc[i][j]);
        }

        // scale + causal mask + per-row max (this wave-half's 64 cols)
        float rmax[4][4];
#pragma unroll
        for (int i = 0; i < 4; i++)
#pragma unroll
            for (int r = 0; r < 4; r++) {
                int qrow = q0 + wr * 64 + i * 16 + quad * 4 + r;
                float mx = -3e38f;
#pragma unroll
                for (int j = 0; j < 4; j++) {
                    int kcol = k0 + wc * 64 + j * 16 + l16;
                    float v = sc[i][j][r] * scale;
                    v = (kcol <= qrow) ? v : -3e38f;
                    sc[i][j][r] = v;
                    mx = fmaxf(mx, v);
                }
#pragma unroll
                for (int dlt = 1; dlt < 16; dlt <<= 1)
                    mx = fmaxf(mx, __shfl_xor(mx, dlt, 64));
                rmax[i][r] = mx;
            }
        if (l16 == 0) {
#pragma unroll
            for (int i = 0; i < 4; i++)
#pragma unroll
                for (int r = 0; r < 4; r++)
                    sRed[wc][wr * 64 + i * 16 + quad * 4 + r] = rmax[i][r];
        }
        __syncthreads();                            // B2

        float alpha[4][4], rsum[4][4], mnv[4][4];
#pragma unroll
        for (int i = 0; i < 4; i++)
#pragma unroll
            for (int r = 0; r < 4; r++) {
                int row = wr * 64 + i * 16 + quad * 4 + r;
                float tm = fmaxf(rmax[i][r], sRed[1 - wc][row]);
                float mo = sM[row];
                float mn = fmaxf(mo, tm);
                mnv[i][r] = mn;
                alpha[i][r] = __expf(mo - mn);
                float s = 0.f;
#pragma unroll
                for (int j = 0; j < 4; j++) {
                    float pv = __expf(sc[i][j][r] - mn);
                    sc[i][j][r] = pv;
                    s += pv;
                }
#pragma unroll
                for (int dlt = 1; dlt < 16; dlt <<= 1)
                    s += __shfl_xor(s, dlt, 64);
                rsum[i][r] = s;
            }
        __syncthreads();                            // B3 (all max reads done)
        if (l16 == 0) {
#pragma unroll
            for (int i = 0; i < 4; i++)
#pragma unroll
                for (int r = 0; r < 4; r++)
                    sRed[wc][wr * 64 + i * 16 + quad * 4 + r] = rsum[i][r];
        }
        // write P (bf16) into sK region, blocked layout [kb][row][8]
#pragma unroll
        for (int i = 0; i < 4; i++)
#pragma unroll
            for (int j = 0; j < 4; j++)
#pragma unroll
                for (int r = 0; r < 4; r++) {
                    int row = wr * 64 + i * 16 + quad * 4 + r;
                    int col = wc * 64 + j * 16 + l16;
                    sK[(col >> 3) * 1024 + row * 8 + (col & 7)] = f2bf(sc[i][j][r]);
                }
        // rescale O
#pragma unroll
        for (int i = 0; i < 4; i++)
#pragma unroll
            for (int j = 0; j < 4; j++)
#pragma unroll
                for (int r = 0; r < 4; r++) o[i][j][r] *= alpha[i][r];
        __syncthreads();                            // B4 (P + sums visible)
        if (wc == 0 && l16 == 0) {
#pragma unroll
            for (int i = 0; i < 4; i++)
#pragma unroll
                for (int r = 0; r < 4; r++) {
                    int row = wr * 64 + i * 16 + quad * 4 + r;
                    float tot = rsum[i][r] + sRed[1][row];
                    sM[row] = mnv[i][r];
                    sL[row] = alpha[i][r] * sL[row] + tot;
                }
        }
        // O += P @ V^T-tile (P blocked in sK; V row-major swizzled in sV)
#pragma unroll
        for (int kk = 0; kk < 4; kk++) {
            int cs = ((kk * 4 + quad) ^ fsw) * 8;
            bf16x8 af[4], bfv[4];
#pragma unroll
            for (int i = 0; i < 4; i++)
                af[i] = *(const bf16x8*)&sK[(kk * 4 + quad) * 1024 + (wr * 64 + i * 16 + l16) * 8];
#pragma unroll
            for (int j = 0; j < 4; j++)
                bfv[j] = *(const bf16x8*)&sV[(wc * 64 + j * 16 + l16) * 128 + cs];
#pragma unroll
            for (int i = 0; i < 4; i++)
#pragma unroll
                for (int j = 0; j < 4; j++)
                    o[i][j] = MFMA16(af[i], bfv[j], o[i][j]);
        }
        __syncthreads();                            // B5
    }

#pragma unroll
    for (int i = 0; i < 4; i++)
#pragma unroll
        for (int r = 0; r < 4; r++) {
            int row = wr * 64 + i * 16 + quad * 4 + r;
            float inv = 1.f / sL[row];
#pragma unroll
            for (int j = 0; j < 4; j++) {
                int n = h * HDIM + wc * 64 + j * 16 + l16;
                ctx[(size_t)(q0 + row) * D_MODEL + n] = f2bf(o[i][j][r] * inv);
            }
        }
}

// ---------- host launch ----------
extern "C" void kernel_launch(void* const* d_in, const int* in_sizes, int n_in,
                              void* d_out, int out_size, void* d_ws, size_t ws_size,
                              hipStream_t stream)
{
    const float* x    = (const float*)d_in[0];
    const float* fcos = (const float*)d_in[2];
    const float* fsin = (const float*)d_in[3];
    const float* wq   = (const float*)d_in[4];
    const float* wk   = (const float*)d_in[5];
    const float* wv   = (const float*)d_in[6];
    const float* wo   = (const float*)d_in[7];
    const float* w1   = (const float*)d_in[8];
    const float* w2   = (const float*)d_in[9];
    const float* w3   = (const float*)d_in[10];
    const float* anw  = (const float*)d_in[11];
    const float* fnw  = (const float*)d_in[12];
    float* out = (float*)d_out;

    const size_t MB = 1024 * 1024;
    char* base = (char*)d_ws;
    u16*   qkvT = (u16*)  (base + 0);          // 24 MB  [6144][2048] bf16
    u16*   woT  = (u16*)  (base + 24 * MB);    //  8 MB
    u16*   w1T  = (u16*)  (base + 32 * MB);    // 32 MB
    u16*   w3T  = (u16*)  (base + 64 * MB);    // 32 MB
    u16*   w2T  = (u16*)  (base + 96 * MB);    // 32 MB
    u16*   nx   = (u16*)  (base + 128 * MB);   //  8 MB
    u16*   qkv  = (u16*)  (base + 136 * MB);   // 24 MB  [2048][6144] bf16
    u16*   vtb  = (u16*)  (base + 160 * MB);   //  8 MB
    u16*   ctxb = (u16*)  (base + 168 * MB);   //  8 MB
    float* x1   = (float*)(base + 176 * MB);   // 16 MB
    u16*   nx2  = (u16*)  (base + 192 * MB);   //  8 MB
    u16*   h1b  = (u16*)  (base + 200 * MB);   // 32 MB
    u16*   hb   = (u16*)  (base + 232 * MB);   // 32 MB -> total 264 MB
    // split-K partials (64 MB f32) alias [0,64) MB — dead before w2 GEMM.
    float* part = (float*)(base + 0);

    dim3 blk(256);

    rmsnorm_kernel<<<SEQ, blk, 0, stream>>>(x, anw, nx);
    tcvt_kernel<<<dim3(64, 64),  blk, 0, stream>>>(wq, qkvT,                       D_MODEL, D_MODEL);
    tcvt_kernel<<<dim3(64, 64),  blk, 0, stream>>>(wk, qkvT + 2048 * 2048,         D_MODEL, D_MODEL);
    tcvt_kernel<<<dim3(64, 64),  blk, 0, stream>>>(wv, qkvT + (size_t)4096 * 2048, D_MODEL, D_MODEL);
    tcvt_kernel<<<dim3(64, 64),  blk, 0, stream>>>(wo, woT, D_MODEL, D_MODEL);
    tcvt_kernel<<<dim3(256, 64), blk, 0, stream>>>(w1, w1T, D_MODEL, IDIM);
    tcvt_kernel<<<dim3(256, 64), blk, 0, stream>>>(w3, w3T, D_MODEL, IDIM);
    tcvt_kernel<<<dim3(64, 256), blk, 0, stream>>>(w2, w2T, IDIM, D_MODEL);

    // fused QKV projection: [2048][6144]
    gemm_bt<128, 0><<<dim3(48, 16), blk, 0, stream>>>(
        nx, qkvT, nullptr, nullptr, nullptr, qkv, SEQ, QKV_LD, D_MODEL, D_MODEL, D_MODEL);

    rope_kernel<<<SEQ, blk, 0, stream>>>(qkv, fcos, fsin);
    tbf16_kernel<<<dim3(64, 64), blk, 0, stream>>>(qkv + 4096, vtb, SEQ, D_MODEL, QKV_LD);

    attn_kernel<<<dim3(16, 16), blk, 0, stream>>>(qkv, qkv + 2048, vtb, ctxb);

    // wo projection + residual (BM=64 -> 512 blocks)
    gemm_bt<64, 1><<<dim3(16, 32), blk, 0, stream>>>(
        ctxb, woT, x, nullptr, x1, nullptr, SEQ, D_MODEL, D_MODEL, D_MODEL, D_MODEL);

    rmsnorm_kernel<<<SEQ, blk, 0, stream>>>(x1, fnw, nx2);

    // FFN: h1 = nx2@w1T ; h = silu(h1) * (nx2@w3T)
    gemm_bt<128, 0><<<dim3(64, 16), blk, 0, stream>>>(
        nx2, w1T, nullptr, nullptr, nullptr, h1b, SEQ, IDIM, D_MODEL, D_MODEL, D_MODEL);
    gemm_bt<128, 2><<<dim3(64, 16), blk, 0, stream>>>(
        nx2, w3T, nullptr, h1b, nullptr, hb, SEQ, IDIM, D_MODEL, D_MODEL, D_MODEL);

    // w2 GEMM split-K x4, then reduce + residual
    gemm_bt<128, 3><<<dim3(16, 16, 4), blk, 0, stream>>>(
        hb, w2T, nullptr, nullptr, part, nullptr, SEQ, D_MODEL, 2048, IDIM, IDIM);
    reduce4_kernel<<<dim3(4096), blk, 0, stream>>>(x1, part, out);
}